// Round 4
// baseline (261.645 us; speedup 1.0000x reference)
//
#include <hip/hip_runtime.h>
#include <cstdint>
#include <cstddef>

typedef unsigned short u16;
typedef short bf16x8 __attribute__((ext_vector_type(8)));
typedef unsigned short u16x8 __attribute__((ext_vector_type(8)));
typedef float f32x4 __attribute__((ext_vector_type(4)));
typedef float f32x16 __attribute__((ext_vector_type(16)));

__device__ __forceinline__ u16 f2bf(float x) {
    union { float f; unsigned int u; } v; v.f = x;
    unsigned int u = v.u;
    unsigned int r = (u + 0x7fffu + ((u >> 16) & 1u)) >> 16;
    return (u16)r;
}

__device__ __forceinline__ unsigned cvtpk(float lo, float hi) {
    unsigned r;
    asm("v_cvt_pk_bf16_f32 %0, %1, %2" : "=v"(r) : "v"(lo), "v"(hi));
    return r;
}

// async global->LDS, 16B per lane. dest = wave-uniform base; lane i lands at base + i*16B.
__device__ __forceinline__ void load_lds16(const void* g, void* l) {
    __builtin_amdgcn_global_load_lds((const __attribute__((address_space(1))) void*)g,
                                     (__attribute__((address_space(3))) void*)l, 16, 0, 0);
}

// ---------------- cast fp32 -> bf16 ----------------
__global__ void cast_f32_bf16(const float* __restrict__ in, u16* __restrict__ out, int n) {
    int i = (blockIdx.x * blockDim.x + threadIdx.x) * 4;
    int stride = gridDim.x * blockDim.x * 4;
    for (; i < n; i += stride) {
        float4 f = *reinterpret_cast<const float4*>(in + i);
        ushort4 o;
        o.x = f2bf(f.x); o.y = f2bf(f.y); o.z = f2bf(f.z); o.w = f2bf(f.w);
        *reinterpret_cast<ushort4*>(out + i) = o;
    }
}

// ---------------- bf16 GEMM: C[M,N] = A[M,K] @ B[N,K]^T ----------------
// MODE 0: fp32 out. MODE 1: merged QKV; Q cols pre-scaled by log2e/8; V written transposed.
template <int MODE>
__global__ __launch_bounds__(256) void gemm_bt(const u16* __restrict__ A,
                                               const u16* __restrict__ Bw,
                                               void* __restrict__ outp,
                                               u16* __restrict__ vtg,
                                               int M, int N, int K) {
    __shared__ u16 smem[16384];
    u16* As = smem;
    u16* Bs = smem + 4096;

    const int tid  = threadIdx.x;
    const int m0   = blockIdx.x * 128;
    const int n0   = blockIdx.y * 128;
    const int wid  = tid >> 6;
    const int lane = tid & 63;
    const int wr   = (wid >> 1) * 64;
    const int wc   = (wid & 1) * 64;
    const int fr   = lane & 15;
    const int ko   = (lane >> 4) * 8;
    const int rq   = (lane >> 4) * 4;

    f32x4 acc[4][4];
#pragma unroll
    for (int i = 0; i < 4; ++i)
#pragma unroll
        for (int j = 0; j < 4; ++j) acc[i][j] = f32x4{0.f, 0.f, 0.f, 0.f};

    const int lr4 = lane >> 2;
    const int ls  = lane & 3;

    for (int k0 = 0; k0 < K; k0 += 32) {
#pragma unroll
        for (int t = 0; t < 2; ++t) {
            const int qtr = wid * 2 + t;
            const int r   = qtr * 16 + lr4;
            load_lds16(&A[(size_t)(m0 + r) * K + k0 + ls * 8], &As[qtr * 512]);
            load_lds16(&Bw[(size_t)(n0 + r) * K + k0 + ls * 8], &Bs[qtr * 512]);
        }
        __syncthreads();

        bf16x8 af[4], bfr[4];
#pragma unroll
        for (int mf = 0; mf < 4; ++mf)
            af[mf] = *reinterpret_cast<const bf16x8*>(&As[(wr + mf * 16 + fr) * 32 + ko]);
#pragma unroll
        for (int nf = 0; nf < 4; ++nf)
            bfr[nf] = *reinterpret_cast<const bf16x8*>(&Bs[(wc + nf * 16 + fr) * 32 + ko]);
        __builtin_amdgcn_s_setprio(1);
#pragma unroll
        for (int mf = 0; mf < 4; ++mf)
#pragma unroll
            for (int nf = 0; nf < 4; ++nf)
                acc[mf][nf] = __builtin_amdgcn_mfma_f32_16x16x32_bf16(
                    af[mf], bfr[nf], acc[mf][nf], 0, 0, 0);
        __builtin_amdgcn_s_setprio(0);
        __syncthreads();
    }

    if constexpr (MODE == 0) {
        float* C = (float*)outp;
#pragma unroll
        for (int mf = 0; mf < 4; ++mf)
#pragma unroll
            for (int nf = 0; nf < 4; ++nf)
#pragma unroll
                for (int i = 0; i < 4; ++i)
                    C[(size_t)(m0 + wr + mf * 16 + rq + i) * N + n0 + wc + nf * 16 + fr] =
                        acc[mf][nf][i];
    } else {
        if (n0 < 2048) {
            const float osc = (n0 < 1024) ? 0.18033688011112042f : 1.0f;  // log2(e)/8 on Q
            u16* qk = (u16*)outp;
#pragma unroll
            for (int mf = 0; mf < 4; ++mf)
#pragma unroll
                for (int nf = 0; nf < 4; ++nf)
#pragma unroll
                    for (int i = 0; i < 4; ++i)
                        qk[(size_t)(m0 + wr + mf * 16 + rq + i) * 2048 + n0 + wc + nf * 16 + fr] =
                            f2bf(acc[mf][nf][i] * osc);
        } else {
            // transpose 128x128 tile through LDS (swizzled), write V^T
#pragma unroll
            for (int mf = 0; mf < 4; ++mf)
#pragma unroll
                for (int nf = 0; nf < 4; ++nf)
#pragma unroll
                    for (int i = 0; i < 4; ++i) {
                        const int nl = wc + nf * 16 + fr;
                        const int ml = wr + mf * 16 + rq + i;
                        smem[nl * 128 + ((((ml * 2) ^ ((nl & 15) << 4))) >> 1)] =
                            f2bf(acc[mf][nf][i]);
                    }
            __syncthreads();
            const int bb   = m0 >> 11;
            const int tloc = m0 & 2047;
#pragma unroll
            for (int p = 0; p < 8; ++p) {
                const int nl = (tid >> 4) + p * 16;
                const int sl = tid & 15;
                u16x8 v = *reinterpret_cast<const u16x8*>(
                    &smem[nl * 128 + ((((sl * 16) ^ ((nl & 15) << 4))) >> 1)]);
                *reinterpret_cast<u16x8*>(
                    &vtg[(size_t)(bb * 1024 + (n0 - 2048) + nl) * 2048 + tloc + sl * 8]) = v;
            }
        }
    }
}

// ---------------- causal flash attention (32x32 swapped QK^T, fixed-max) ----------------
// qk: [B*T, 2048] bf16 (Q cols 0..1023 PRE-SCALED by log2e/8, K cols 1024..2047)
// vtg: [B*16*64, 2048] = V^T per (b,h). Y: [B*T, 1024] bf16.
// grid (16, 64): block handles one 128-row q tile (descending: long blocks first).
// Wave w owns q rows [w*32, w*32+32). KV tiles of 64, double-buffered.
__global__ __launch_bounds__(256) void attn_fwd(const u16* __restrict__ qk,
                                                const u16* __restrict__ vtg,
                                                u16* __restrict__ Y) {
    constexpr int T = 2048, DQK = 2048, DOUT = 1024;
    const int qt = (int)gridDim.x - 1 - (int)blockIdx.x;
    const int bh = blockIdx.y;
    const int b  = bh >> 4, hd = bh & 15;
    const int tid = threadIdx.x, w = tid >> 6, lane = tid & 63;
    const int qloc = lane & 31, h2 = lane >> 5;

    __shared__ u16 Ks[2][4096];   // [64 kv][64 d] linear, slot^(row&7) swizzle
    __shared__ u16 Vs[2][4096];   // [64 d][64 kv] linear, same swizzle

    const int q0 = qt * 128;
    const int wq = q0 + w * 32;           // wave's global q base
    const int NT = 2 * qt + 2;
    const size_t rowb = (size_t)b * T;
    const int sr8 = lane >> 3, ss = lane & 7;

    // Q as B-fragment: col=lane&31 (q row), k = ks*16 + h2*8 + j
    bf16x8 qf[4];
#pragma unroll
    for (int ks = 0; ks < 4; ++ks)
        qf[ks] = *reinterpret_cast<const bf16x8*>(
            &qk[(rowb + wq + qloc) * DQK + hd * 64 + ks * 16 + h2 * 8]);

    f32x16 o0, o1;
#pragma unroll
    for (int i = 0; i < 16; ++i) { o0[i] = 0.f; o1[i] = 0.f; }
    float lp = 0.f;   // per-lane l partial (q = lane&31; this half's kv rows)

    // prologue: stage tile 0 into buf 0
    {
        const int qtr = w * 2, r0 = qtr * 8 + sr8, r1 = r0 + 8;
        const int sc0 = (ss ^ (r0 & 7)) * 8, sc1 = (ss ^ (r1 & 7)) * 8;
        load_lds16(&qk[(rowb + r0) * DQK + 1024 + hd * 64 + sc0], &Ks[0][qtr * 512]);
        load_lds16(&vtg[((size_t)bh * 64 + r0) * T + sc0], &Vs[0][qtr * 512]);
        load_lds16(&qk[(rowb + r1) * DQK + 1024 + hd * 64 + sc1], &Ks[0][(qtr + 1) * 512]);
        load_lds16(&vtg[((size_t)bh * 64 + r1) * T + sc1], &Vs[0][(qtr + 1) * 512]);
    }

#define BUILD_PA(sv, RB, dst) {                                               \
        unsigned wa = cvtpk(sv[RB + 0], sv[RB + 1]);                          \
        unsigned wb = cvtpk(sv[RB + 2], sv[RB + 3]);                          \
        unsigned wc2 = cvtpk(sv[RB + 4], sv[RB + 5]);                         \
        unsigned wd = cvtpk(sv[RB + 6], sv[RB + 7]);                          \
        unsigned wax = (unsigned)__shfl_xor((int)wa, 32);                     \
        unsigned wbx = (unsigned)__shfl_xor((int)wb, 32);                     \
        unsigned wcx = (unsigned)__shfl_xor((int)wc2, 32);                    \
        unsigned wdx = (unsigned)__shfl_xor((int)wd, 32);                     \
        dst.x = h2 ? wcx : wa;  dst.y = h2 ? wdx : wb;                        \
        dst.z = h2 ? wc2 : wax; dst.w = h2 ? wd : wbx; }

#define PV_STEP(pa, KS, ROWBASE, oacc) {                                      \
        const int rr_ = (ROWBASE) + qloc;                                     \
        bf16x8 vf_ = *reinterpret_cast<const bf16x8*>(                        \
            &Vb[rr_ * 64 + (((2 * (KS) + h2) ^ (rr_ & 7)) * 8)]);             \
        oacc = __builtin_amdgcn_mfma_f32_32x32x16_bf16(                       \
            *reinterpret_cast<const bf16x8*>(&pa), vf_, oacc, 0, 0, 0); }

    for (int kt = 0; kt < NT; ++kt) {
        __syncthreads();   // stage(kt) complete; all waves done with compute(kt-1)

        if (kt + 1 < NT) {
            const int nb = (kt + 1) & 1;
            const int k0n = (kt + 1) * 64;
            const int qtr = w * 2, r0 = qtr * 8 + sr8, r1 = r0 + 8;
            const int sc0 = (ss ^ (r0 & 7)) * 8, sc1 = (ss ^ (r1 & 7)) * 8;
            load_lds16(&qk[(rowb + k0n + r0) * DQK + 1024 + hd * 64 + sc0], &Ks[nb][qtr * 512]);
            load_lds16(&vtg[((size_t)bh * 64 + r0) * T + k0n + sc0], &Vs[nb][qtr * 512]);
            load_lds16(&qk[(rowb + k0n + r1) * DQK + 1024 + hd * 64 + sc1], &Ks[nb][(qtr + 1) * 512]);
            load_lds16(&vtg[((size_t)bh * 64 + r1) * T + k0n + sc1], &Vs[nb][(qtr + 1) * 512]);
        }

        const int k0 = kt * 64;
        if (k0 <= wq + 31) {                       // wave-uniform tile skip
            const u16* Kb = Ks[kt & 1];
            const u16* Vb = Vs[kt & 1];
            const bool do1 = (k0 + 32 <= wq + 31); // kv block [k0+32,k0+64) has unmasked?
            const bool dm  = (k0 + 63 > wq);       // needs causal masking

            // S^T = K * Q  (A = K rows=kv, B = Q cols=q)
            f32x16 st0, st1;
#pragma unroll
            for (int i = 0; i < 16; ++i) { st0[i] = 0.f; st1[i] = 0.f; }

            __builtin_amdgcn_s_setprio(1);
#pragma unroll
            for (int ks = 0; ks < 4; ++ks) {
                bf16x8 kf = *reinterpret_cast<const bf16x8*>(
                    &Kb[qloc * 64 + (((2 * ks + h2) ^ (qloc & 7)) * 8)]);
                st0 = __builtin_amdgcn_mfma_f32_32x32x16_bf16(kf, qf[ks], st0, 0, 0, 0);
            }
            if (do1) {
#pragma unroll
                for (int ks = 0; ks < 4; ++ks) {
                    const int r1 = 32 + qloc;
                    bf16x8 kf = *reinterpret_cast<const bf16x8*>(
                        &Kb[r1 * 64 + (((2 * ks + h2) ^ (r1 & 7)) * 8)]);
                    st1 = __builtin_amdgcn_mfma_f32_32x32x16_bf16(kf, qf[ks], st1, 0, 0, 0);
                }
            }
            __builtin_amdgcn_s_setprio(0);

            // p = exp2(s) (Q pre-scaled; fixed-max shift=0 is safe), causal mask, l partials
            const int qg = wq + qloc;
#pragma unroll
            for (int i = 0; i < 16; ++i) st0[i] = exp2f(st0[i]);
            if (do1) {
#pragma unroll
                for (int i = 0; i < 16; ++i) st1[i] = exp2f(st1[i]);
            }
            if (dm) {
#pragma unroll
                for (int r = 0; r < 16; ++r) {
                    const int crow = (r & 3) + 8 * (r >> 2) + 4 * h2;
                    if (k0 + crow > qg)      st0[r] = 0.f;
                    if (k0 + 32 + crow > qg) st1[r] = 0.f;
                }
            }
            {
                float l0 = 0.f, l1 = 0.f, l2 = 0.f, l3 = 0.f;
#pragma unroll
                for (int i = 0; i < 4; ++i) {
                    l0 += st0[i]; l1 += st0[4 + i]; l2 += st0[8 + i]; l3 += st0[12 + i];
                }
                if (do1) {
#pragma unroll
                    for (int i = 0; i < 4; ++i) {
                        l0 += st1[i]; l1 += st1[4 + i]; l2 += st1[8 + i]; l3 += st1[12 + i];
                    }
                }
                lp += (l0 + l1) + (l2 + l3);
            }

            // P -> bf16 A-fragments in-register (cvt_pk + half-exchange)
            uint4 pa0, pa1, pa2, pa3;
            BUILD_PA(st0, 0, pa0);
            BUILD_PA(st0, 8, pa1);
            if (do1) {
                BUILD_PA(st1, 0, pa2);
                BUILD_PA(st1, 8, pa3);
            }

            // O += P * V   (A = P rows=q, B = V cols=d)
            __builtin_amdgcn_s_setprio(1);
            PV_STEP(pa0, 0, 0, o0);
            PV_STEP(pa1, 1, 0, o0);
            PV_STEP(pa0, 0, 32, o1);
            PV_STEP(pa1, 1, 32, o1);
            if (do1) {
                PV_STEP(pa2, 2, 0, o0);
                PV_STEP(pa3, 3, 0, o0);
                PV_STEP(pa2, 2, 32, o1);
                PV_STEP(pa3, 3, 32, o1);
            }
            __builtin_amdgcn_s_setprio(0);
        }
    }

    // epilogue: finish l, divide, store
    const float lf = lp + __shfl_xor(lp, 32);
    const float linv = 1.0f / lf;
#pragma unroll
    for (int r = 0; r < 16; ++r) {
        const int crow = (r & 3) + 8 * (r >> 2) + 4 * h2;
        const float rl = __shfl(linv, crow);     // linv of q-row crow (same in both halves)
        const size_t yrow = rowb + wq + crow;
        Y[yrow * DOUT + hd * 64 + qloc]      = f2bf(o0[r] * rl);
        Y[yrow * DOUT + hd * 64 + 32 + qloc] = f2bf(o1[r] * rl);
    }
#undef BUILD_PA
#undef PV_STEP
}

extern "C" void kernel_launch(void* const* d_in, const int* in_sizes, int n_in,
                              void* d_out, int out_size, void* d_ws, size_t ws_size,
                              hipStream_t stream) {
    const float* x  = (const float*)d_in[0];
    const float* Wq = (const float*)d_in[1];
    const float* Wk = (const float*)d_in[2];
    const float* Wv = (const float*)d_in[3];
    const float* Wo = (const float*)d_in[4];

    constexpr int B = 4, T = 2048, D = 1024;
    constexpr int M = B * T;
    const int nx = in_sizes[0];
    const int nw = in_sizes[1];

    char* ws = (char*)d_ws;
    u16* xb   = (u16*)(ws);
    u16* qkb  = (u16*)(ws + (16ull << 20));
    u16* vtg  = (u16*)(ws + (48ull << 20));
    u16* yb   = (u16*)(ws + (64ull << 20));
    u16* wqkv = (u16*)(ws + (80ull << 20));
    u16* wob  = (u16*)(ws + (86ull << 20));

    cast_f32_bf16<<<2048, 256, 0, stream>>>(x, xb, nx);
    cast_f32_bf16<<<512, 256, 0, stream>>>(Wq, wqkv, nw);
    cast_f32_bf16<<<512, 256, 0, stream>>>(Wk, wqkv + (size_t)nw, nw);
    cast_f32_bf16<<<512, 256, 0, stream>>>(Wv, wqkv + 2 * (size_t)nw, nw);
    cast_f32_bf16<<<512, 256, 0, stream>>>(Wo, wob, nw);

    gemm_bt<1><<<dim3(M / 128, 3072 / 128), 256, 0, stream>>>(xb, wqkv, qkb, vtg, M, 3072, D);

    attn_fwd<<<dim3(16, B * 16), 256, 0, stream>>>(qkb, vtg, yb);

    gemm_bt<0><<<dim3(M / 128, D / 128), 256, 0, stream>>>(yb, wob, d_out, nullptr, M, D, D);
}

// Round 5
// 168.537 us; speedup vs baseline: 1.5525x; 1.5525x over previous
//
#include <hip/hip_runtime.h>
#include <cstdint>
#include <cstddef>

typedef unsigned short u16;
typedef short bf16x8 __attribute__((ext_vector_type(8)));
typedef unsigned short u16x8 __attribute__((ext_vector_type(8)));
typedef float f32x4 __attribute__((ext_vector_type(4)));
typedef float f32x16 __attribute__((ext_vector_type(16)));
typedef unsigned u32x2 __attribute__((ext_vector_type(2)));

__device__ __forceinline__ u16 f2bf(float x) {
    union { float f; unsigned int u; } v; v.f = x;
    unsigned int u = v.u;
    unsigned int r = (u + 0x7fffu + ((u >> 16) & 1u)) >> 16;
    return (u16)r;
}

__device__ __forceinline__ unsigned cvtpk(float lo, float hi) {
    unsigned r;
    asm("v_cvt_pk_bf16_f32 %0, %1, %2" : "=v"(r) : "v"(lo), "v"(hi));
    return r;
}

__device__ __forceinline__ float exp2v(float x) {
    float y;
    asm("v_exp_f32 %0, %1" : "=v"(y) : "v"(x));
    return y;
}

// async global->LDS, 16B per lane. dest = wave-uniform base; lane i lands at base + i*16B.
__device__ __forceinline__ void load_lds16(const void* g, void* l) {
    __builtin_amdgcn_global_load_lds((const __attribute__((address_space(1))) void*)g,
                                     (__attribute__((address_space(3))) void*)l, 16, 0, 0);
}

// ---------------- casts ----------------
__global__ void cast_f32_bf16(const float* __restrict__ in, u16* __restrict__ out, int n) {
    int i = (blockIdx.x * blockDim.x + threadIdx.x) * 4;
    int stride = gridDim.x * blockDim.x * 4;
    for (; i < n; i += stride) {
        float4 f = *reinterpret_cast<const float4*>(in + i);
        ushort4 o;
        o.x = f2bf(f.x); o.y = f2bf(f.y); o.z = f2bf(f.z); o.w = f2bf(f.w);
        *reinterpret_cast<ushort4*>(out + i) = o;
    }
}

// 4 weights in one launch: blockIdx.y selects the weight (wave-uniform pointer select)
__global__ void cast_w4(const float* __restrict__ w0, const float* __restrict__ w1,
                        const float* __restrict__ w2, const float* __restrict__ w3,
                        u16* __restrict__ out, int nw) {
    const int wsel = blockIdx.y;
    const float* in = (wsel == 0) ? w0 : (wsel == 1) ? w1 : (wsel == 2) ? w2 : w3;
    u16* o = out + (size_t)wsel * nw;
    int i = (blockIdx.x * blockDim.x + threadIdx.x) * 4;
    int stride = gridDim.x * blockDim.x * 4;
    for (; i < nw; i += stride) {
        float4 f = *reinterpret_cast<const float4*>(in + i);
        ushort4 v;
        v.x = f2bf(f.x); v.y = f2bf(f.y); v.z = f2bf(f.z); v.w = f2bf(f.w);
        *reinterpret_cast<ushort4*>(o + i) = v;
    }
}

// ---------------- bf16 GEMM: C[M,N] = A[M,K] @ B[N,K]^T ----------------
// MODE 0: fp32 out. MODE 1: merged QKV; Q cols pre-scaled by log2e/8; V written transposed.
template <int MODE>
__global__ __launch_bounds__(256) void gemm_bt(const u16* __restrict__ A,
                                               const u16* __restrict__ Bw,
                                               void* __restrict__ outp,
                                               u16* __restrict__ vtg,
                                               int M, int N, int K) {
    __shared__ u16 smem[16384];
    u16* As = smem;
    u16* Bs = smem + 4096;

    const int tid  = threadIdx.x;
    const int m0   = blockIdx.x * 128;
    const int n0   = blockIdx.y * 128;
    const int wid  = tid >> 6;
    const int lane = tid & 63;
    const int wr   = (wid >> 1) * 64;
    const int wc   = (wid & 1) * 64;
    const int fr   = lane & 15;
    const int ko   = (lane >> 4) * 8;
    const int rq   = (lane >> 4) * 4;

    f32x4 acc[4][4];
#pragma unroll
    for (int i = 0; i < 4; ++i)
#pragma unroll
        for (int j = 0; j < 4; ++j) acc[i][j] = f32x4{0.f, 0.f, 0.f, 0.f};

    const int lr4 = lane >> 2;
    const int ls  = lane & 3;

    for (int k0 = 0; k0 < K; k0 += 32) {
#pragma unroll
        for (int t = 0; t < 2; ++t) {
            const int qtr = wid * 2 + t;
            const int r   = qtr * 16 + lr4;
            load_lds16(&A[(size_t)(m0 + r) * K + k0 + ls * 8], &As[qtr * 512]);
            load_lds16(&Bw[(size_t)(n0 + r) * K + k0 + ls * 8], &Bs[qtr * 512]);
        }
        __syncthreads();

        bf16x8 af[4], bfr[4];
#pragma unroll
        for (int mf = 0; mf < 4; ++mf)
            af[mf] = *reinterpret_cast<const bf16x8*>(&As[(wr + mf * 16 + fr) * 32 + ko]);
#pragma unroll
        for (int nf = 0; nf < 4; ++nf)
            bfr[nf] = *reinterpret_cast<const bf16x8*>(&Bs[(wc + nf * 16 + fr) * 32 + ko]);
        __builtin_amdgcn_s_setprio(1);
#pragma unroll
        for (int mf = 0; mf < 4; ++mf)
#pragma unroll
            for (int nf = 0; nf < 4; ++nf)
                acc[mf][nf] = __builtin_amdgcn_mfma_f32_16x16x32_bf16(
                    af[mf], bfr[nf], acc[mf][nf], 0, 0, 0);
        __builtin_amdgcn_s_setprio(0);
        __syncthreads();
    }

    if constexpr (MODE == 0) {
        float* C = (float*)outp;
#pragma unroll
        for (int mf = 0; mf < 4; ++mf)
#pragma unroll
            for (int nf = 0; nf < 4; ++nf)
#pragma unroll
                for (int i = 0; i < 4; ++i)
                    C[(size_t)(m0 + wr + mf * 16 + rq + i) * N + n0 + wc + nf * 16 + fr] =
                        acc[mf][nf][i];
    } else {
        if (n0 < 2048) {
            const float osc = (n0 < 1024) ? 0.18033688011112042f : 1.0f;  // log2(e)/8 on Q
            u16* qk = (u16*)outp;
#pragma unroll
            for (int mf = 0; mf < 4; ++mf)
#pragma unroll
                for (int nf = 0; nf < 4; ++nf)
#pragma unroll
                    for (int i = 0; i < 4; ++i)
                        qk[(size_t)(m0 + wr + mf * 16 + rq + i) * 2048 + n0 + wc + nf * 16 + fr] =
                            f2bf(acc[mf][nf][i] * osc);
        } else {
            // transpose 128x128 tile through LDS (swizzled), write V^T
#pragma unroll
            for (int mf = 0; mf < 4; ++mf)
#pragma unroll
                for (int nf = 0; nf < 4; ++nf)
#pragma unroll
                    for (int i = 0; i < 4; ++i) {
                        const int nl = wc + nf * 16 + fr;
                        const int ml = wr + mf * 16 + rq + i;
                        smem[nl * 128 + ((((ml * 2) ^ ((nl & 15) << 4))) >> 1)] =
                            f2bf(acc[mf][nf][i]);
                    }
            __syncthreads();
            const int bb   = m0 >> 11;
            const int tloc = m0 & 2047;
#pragma unroll
            for (int p = 0; p < 8; ++p) {
                const int nl = (tid >> 4) + p * 16;
                const int sl = tid & 15;
                u16x8 v = *reinterpret_cast<const u16x8*>(
                    &smem[nl * 128 + ((((sl * 16) ^ ((nl & 15) << 4))) >> 1)]);
                *reinterpret_cast<u16x8*>(
                    &vtg[(size_t)(bb * 1024 + (n0 - 2048) + nl) * 2048 + tloc + sl * 8]) = v;
            }
        }
    }
}

// ---------------- causal flash attention (32x32 swapped QK^T, fixed-max) ----------------
// qk: [B*T, 2048] bf16 (Q pre-scaled by log2e/8, K cols 1024..2047)
// vtg: [B*16*64, 2048] = V^T per (b,h). Y: [B*T, 1024] bf16.
// grid (8, 64): bh = x*8 + (y&7)  (same-bh blocks share an XCD's L2),
//               jb = y>>3; block handles q-tiles {15-jb, jb} (34 KV tiles, balanced).
__global__ __launch_bounds__(256) void attn_fwd(const u16* __restrict__ qk,
                                                const u16* __restrict__ vtg,
                                                u16* __restrict__ Y) {
    constexpr int T = 2048, DQK = 2048, DOUT = 1024;
    const int jb = (int)blockIdx.y >> 3;
    const int bh = (int)blockIdx.x * 8 + ((int)blockIdx.y & 7);
    const int b  = bh >> 4, hd = bh & 15;
    const int tid = threadIdx.x, w = tid >> 6, lane = tid & 63;
    const int qloc = lane & 31, h2 = lane >> 5;

    __shared__ u16 Ks[2][4096];   // [64 kv][64 d] linear, slot^(row&7) swizzle
    __shared__ u16 Vs[2][4096];   // [64 d][64 kv] linear, same swizzle

    const size_t rowb = (size_t)b * T;
    const int sr8 = lane >> 3, ss = lane & 7;

#define BUILD_PA(sv, RB, dst) {                                               \
        unsigned wa  = cvtpk(sv[RB + 0], sv[RB + 1]);                         \
        unsigned wb  = cvtpk(sv[RB + 2], sv[RB + 3]);                         \
        unsigned wc2 = cvtpk(sv[RB + 4], sv[RB + 5]);                         \
        unsigned wd  = cvtpk(sv[RB + 6], sv[RB + 7]);                         \
        u32x2 r0 = __builtin_amdgcn_permlane32_swap(wa, wc2, false, false);   \
        u32x2 r1 = __builtin_amdgcn_permlane32_swap(wb, wd, false, false);    \
        dst.x = r0.x; dst.y = r1.x; dst.z = r0.y; dst.w = r1.y; }

#define PV_STEP(pa, KS, ROWBASE, oacc) {                                      \
        const int rr_ = (ROWBASE) + qloc;                                     \
        bf16x8 vf_ = *reinterpret_cast<const bf16x8*>(                        \
            &Vb[rr_ * 64 + (((2 * (KS) + h2) ^ (rr_ & 7)) * 8)]);             \
        oacc = __builtin_amdgcn_mfma_f32_32x32x16_bf16(                       \
            *reinterpret_cast<const bf16x8*>(&pa), vf_, oacc, 0, 0, 0); }

    for (int qi = 0; qi < 2; ++qi) {
        const int qt = (qi == 0) ? (15 - jb) : jb;
        const int q0 = qt * 128;
        const int wq = q0 + w * 32;
        const int NT = 2 * qt + 2;

        // Q as B-fragment: col=lane&31 (q row), k = ks*16 + h2*8 + j
        bf16x8 qf[4];
#pragma unroll
        for (int ks = 0; ks < 4; ++ks)
            qf[ks] = *reinterpret_cast<const bf16x8*>(
                &qk[(rowb + wq + qloc) * DQK + hd * 64 + ks * 16 + h2 * 8]);

        f32x16 o0, o1;
#pragma unroll
        for (int i = 0; i < 16; ++i) { o0[i] = 0.f; o1[i] = 0.f; }
        float lp = 0.f;

        __syncthreads();   // protect buffers from previous q-tile's compute

        // prologue: stage tile 0 into buf 0
        {
            const int qtr = w * 2, r0 = qtr * 8 + sr8, r1 = r0 + 8;
            const int sc0 = (ss ^ (r0 & 7)) * 8, sc1 = (ss ^ (r1 & 7)) * 8;
            load_lds16(&qk[(rowb + r0) * DQK + 1024 + hd * 64 + sc0], &Ks[0][qtr * 512]);
            load_lds16(&vtg[((size_t)bh * 64 + r0) * T + sc0], &Vs[0][qtr * 512]);
            load_lds16(&qk[(rowb + r1) * DQK + 1024 + hd * 64 + sc1], &Ks[0][(qtr + 1) * 512]);
            load_lds16(&vtg[((size_t)bh * 64 + r1) * T + sc1], &Vs[0][(qtr + 1) * 512]);
        }

        for (int kt = 0; kt < NT; ++kt) {
            __syncthreads();   // stage(kt) complete; all waves done with compute(kt-1)

            if (kt + 1 < NT) {
                const int nb = (kt + 1) & 1;
                const int k0n = (kt + 1) * 64;
                const int qtr = w * 2, r0 = qtr * 8 + sr8, r1 = r0 + 8;
                const int sc0 = (ss ^ (r0 & 7)) * 8, sc1 = (ss ^ (r1 & 7)) * 8;
                load_lds16(&qk[(rowb + k0n + r0) * DQK + 1024 + hd * 64 + sc0], &Ks[nb][qtr * 512]);
                load_lds16(&vtg[((size_t)bh * 64 + r0) * T + k0n + sc0], &Vs[nb][qtr * 512]);
                load_lds16(&qk[(rowb + k0n + r1) * DQK + 1024 + hd * 64 + sc1], &Ks[nb][(qtr + 1) * 512]);
                load_lds16(&vtg[((size_t)bh * 64 + r1) * T + k0n + sc1], &Vs[nb][(qtr + 1) * 512]);
            }

            const int k0 = kt * 64;
            if (k0 <= wq + 31) {                       // wave-uniform tile skip
                const u16* Kb = Ks[kt & 1];
                const u16* Vb = Vs[kt & 1];
                const bool do1 = (k0 + 32 <= wq + 31);
                const bool dm  = (k0 + 63 > wq);

                f32x16 st0, st1;
#pragma unroll
                for (int i = 0; i < 16; ++i) { st0[i] = 0.f; st1[i] = 0.f; }

                __builtin_amdgcn_s_setprio(1);
#pragma unroll
                for (int ks = 0; ks < 4; ++ks) {
                    bf16x8 kf = *reinterpret_cast<const bf16x8*>(
                        &Kb[qloc * 64 + (((2 * ks + h2) ^ (qloc & 7)) * 8)]);
                    st0 = __builtin_amdgcn_mfma_f32_32x32x16_bf16(kf, qf[ks], st0, 0, 0, 0);
                }
                if (do1) {
#pragma unroll
                    for (int ks = 0; ks < 4; ++ks) {
                        const int r1 = 32 + qloc;
                        bf16x8 kf = *reinterpret_cast<const bf16x8*>(
                            &Kb[r1 * 64 + (((2 * ks + h2) ^ (r1 & 7)) * 8)]);
                        st1 = __builtin_amdgcn_mfma_f32_32x32x16_bf16(kf, qf[ks], st1, 0, 0, 0);
                    }
                }
                __builtin_amdgcn_s_setprio(0);

                // p = exp2(s); causal mask; l partials
                const int qg = wq + qloc;
#pragma unroll
                for (int i = 0; i < 16; ++i) st0[i] = exp2v(st0[i]);
                if (do1) {
#pragma unroll
                    for (int i = 0; i < 16; ++i) st1[i] = exp2v(st1[i]);
                }
                if (dm) {
#pragma unroll
                    for (int r = 0; r < 16; ++r) {
                        const int crow = (r & 3) + 8 * (r >> 2) + 4 * h2;
                        if (k0 + crow > qg)      st0[r] = 0.f;
                        if (k0 + 32 + crow > qg) st1[r] = 0.f;
                    }
                }
                {
                    float l0 = 0.f, l1 = 0.f, l2 = 0.f, l3 = 0.f;
#pragma unroll
                    for (int i = 0; i < 4; ++i) {
                        l0 += st0[i]; l1 += st0[4 + i]; l2 += st0[8 + i]; l3 += st0[12 + i];
                    }
                    if (do1) {
#pragma unroll
                        for (int i = 0; i < 4; ++i) {
                            l0 += st1[i]; l1 += st1[4 + i]; l2 += st1[8 + i]; l3 += st1[12 + i];
                        }
                    }
                    lp += (l0 + l1) + (l2 + l3);
                }

                uint4 pa0, pa1, pa2, pa3;
                BUILD_PA(st0, 0, pa0);
                BUILD_PA(st0, 8, pa1);
                if (do1) {
                    BUILD_PA(st1, 0, pa2);
                    BUILD_PA(st1, 8, pa3);
                }

                __builtin_amdgcn_s_setprio(1);
                PV_STEP(pa0, 0, 0, o0);
                PV_STEP(pa1, 1, 0, o0);
                PV_STEP(pa0, 0, 32, o1);
                PV_STEP(pa1, 1, 32, o1);
                if (do1) {
                    PV_STEP(pa2, 2, 0, o0);
                    PV_STEP(pa3, 3, 0, o0);
                    PV_STEP(pa2, 2, 32, o1);
                    PV_STEP(pa3, 3, 32, o1);
                }
                __builtin_amdgcn_s_setprio(0);
            }
        }

        // epilogue: finish l, divide, store
        const float lf = lp + __shfl_xor(lp, 32);
        const float linv = 1.0f / lf;
#pragma unroll
        for (int r = 0; r < 16; ++r) {
            const int crow = (r & 3) + 8 * (r >> 2) + 4 * h2;
            const float rl = __shfl(linv, crow);
            const size_t yrow = rowb + wq + crow;
            Y[yrow * DOUT + hd * 64 + qloc]      = (u16)cvtpk(o0[r] * rl, 0.f);
            Y[yrow * DOUT + hd * 64 + 32 + qloc] = (u16)cvtpk(o1[r] * rl, 0.f);
        }
    }
#undef BUILD_PA
#undef PV_STEP
}

extern "C" void kernel_launch(void* const* d_in, const int* in_sizes, int n_in,
                              void* d_out, int out_size, void* d_ws, size_t ws_size,
                              hipStream_t stream) {
    const float* x  = (const float*)d_in[0];
    const float* Wq = (const float*)d_in[1];
    const float* Wk = (const float*)d_in[2];
    const float* Wv = (const float*)d_in[3];
    const float* Wo = (const float*)d_in[4];

    constexpr int B = 4, T = 2048, D = 1024;
    constexpr int M = B * T;
    const int nx = in_sizes[0];
    const int nw = in_sizes[1];

    char* ws = (char*)d_ws;
    u16* xb   = (u16*)(ws);
    u16* qkb  = (u16*)(ws + (16ull << 20));
    u16* vtg  = (u16*)(ws + (48ull << 20));
    u16* yb   = (u16*)(ws + (64ull << 20));
    u16* wqkv = (u16*)(ws + (80ull << 20));   // 4 weights contiguous: Wq,Wk,Wv then Wo
    u16* wob  = wqkv + 3 * (size_t)nw;

    cast_f32_bf16<<<2048, 256, 0, stream>>>(x, xb, nx);
    cast_w4<<<dim3(256, 4), 256, 0, stream>>>(Wq, Wk, Wv, Wo, wqkv, nw);

    gemm_bt<1><<<dim3(M / 128, 3072 / 128), 256, 0, stream>>>(xb, wqkv, qkb, vtg, M, 3072, D);

    attn_fwd<<<dim3(8, 64), 256, 0, stream>>>(qkb, vtg, yb);

    gemm_bt<0><<<dim3(M / 128, D / 128), 256, 0, stream>>>(yb, wob, d_out, nullptr, M, D, D);
}